// Round 2
// baseline (278.936 us; speedup 1.0000x reference)
//
#include <hip/hip_runtime.h>
#include <stdint.h>

// Cost volume: out[b,k,h,w] = (1/81) * sum_c x1[b,c,h,w] * x2[b,c,h-i,w-j]
// k = (9i+j) mod 81, i,j in [-4,4], zero-padded x2. B=4 C=128 H=128 W=256 fp32.
//
// Round 2 design:
//  - block = 9 waves (576 thr), wave wv handles displacement row i = wv-4.
//  - tile 8h x 64w; lane owns 8 consecutive w pixels -> acc[9][8] (72 regs).
//  - per 1 channel per lane: 6 ds_read_b128 -> 72 FMAs (VALU:LDS = 2:1).
//  - C staged in chunks of 4 channels via __builtin_amdgcn_global_load_lds
//    (width 16), double-buffered LDS, m97 K-loop: sync -> issue k+1 -> compute k.
//  - LDS rows padded: x1 stride 68 (bank shift 4/row), x2 stride 84 (shift 20)
//    so adjacent rows hit complementary bank halves.
//  - OOB halo float4-groups redirected to zeroed d_ws (groups never straddle
//    the image edge: w0 multiple of 64, groups 4-word aligned).
//  - __launch_bounds__(576,4): cap VGPR at 128 so the 9-wave block schedules
//    at 4 waves/SIMD and the compiler has prefetch headroom (round-1 was
//    starved at 52 VGPR -> serialized lgkmcnt stalls).

#define AS1(p) (const __attribute__((address_space(1))) void*)(p)
#define AS3(p) (__attribute__((address_space(3))) void*)(p)

#define HH 128
#define WW 256
#define CCT 128
#define DD 81
#define TH 8
#define TWIDE 64
#define CK 4
#define NT 576

// buf layout (fp32 words): x1 [4][8][68]=2176 | pad 128 | x2 [4][16][84]=5376
#define X1STR 68
#define X2STR 84
#define X1CI 544    // 8*68
#define X2CI 1344   // 16*84
#define X2BASE 2304 // 2176 + 128 pad (absorbs the 32 dummy staging groups)
#define BUFW 7680   // 30720 B per buffer

__global__ __launch_bounds__(NT, 4) void cost_volume_kernel(
    const float* __restrict__ x1, const float* __restrict__ x2,
    float* __restrict__ out, const float* __restrict__ zws) {
  __shared__ float smem[2][BUFW];  // 61440 B

  const int b = blockIdx.z;
  const int h0 = blockIdx.y * TH;
  const int w0 = blockIdx.x * TWIDE;
  const int t = threadIdx.x;
  const int wv = t >> 6;     // 0..8 -> i = wv-4
  const int lane = t & 63;
  const int hl = lane >> 3;  // 0..7 local h row
  const int g = lane & 7;    // 0..7 group of 8 w pixels
  const int r = hl + 8 - wv; // x2 local row for this wave's displacement

  const float* x1b = x1 + (size_t)b * CCT * HH * WW;
  const float* x2b = x2 + (size_t)b * CCT * HH * WW;

  // ---- async staging of one 4-channel chunk into buf ----
  auto stage = [&](int c0, float* buf) {
    // x1: 544 real float4 groups + 32 pad (full 576, full waves)
    {
      const int idx = t;
      const int ci = idx / 136;          // 136 = 8 rows * 17 groups
      const int rem = idx - ci * 136;
      const int row = rem / 17;
      const int c4 = rem - row * 17;
      const int w = w0 + c4 * 4;
      const float* gp = zws;
      if (idx < 544 && w <= WW - 4)
        gp = x1b + (((size_t)(c0 + ci) * HH + (h0 + row)) << 8) + w;
      __builtin_amdgcn_global_load_lds(AS1(gp), AS3(buf + idx * 4), 16, 0, 0);
    }
    // x2: 1344 float4 groups (1344 = 21*64, masking at wave granularity)
#pragma unroll
    for (int it = 0; it < 3; ++it) {
      const int idx = t + it * NT;
      if (idx < 1344) {
        const int ci = idx / 336;        // 336 = 16 rows * 21 groups
        const int rem = idx - ci * 336;
        const int row = rem / 21;
        const int c4 = rem - row * 21;
        const int h = h0 - 4 + row;
        const int w = w0 - 8 + c4 * 4;
        const float* gp = zws;
        if ((unsigned)h < (unsigned)HH && (unsigned)w <= (unsigned)(WW - 4))
          gp = x2b + (((size_t)(c0 + ci) * HH + h) << 8) + w;
        __builtin_amdgcn_global_load_lds(AS1(gp), AS3(buf + X2BASE + idx * 4),
                                         16, 0, 0);
      }
    }
  };

  float acc[9][8];
#pragma unroll
  for (int jj = 0; jj < 9; ++jj)
#pragma unroll
    for (int p = 0; p < 8; ++p) acc[jj][p] = 0.f;

  const int o1 = hl * X1STR + g * 8;
  const int o2 = r * X2STR + g * 8 + 4;

  stage(0, smem[0]);

  for (int k = 0; k < CCT / CK; ++k) {
    __syncthreads();  // drains stage(k) (vmcnt0) + protects buffer reuse
    if (k < CCT / CK - 1) stage((k + 1) * CK, smem[(k + 1) & 1]);
    const float* x1s = smem[k & 1];
    const float* x2s = smem[k & 1] + X2BASE;
#pragma unroll
    for (int ci = 0; ci < CK; ++ci) {
      float xv[8], v[16];
      *(float4*)&xv[0] = *(const float4*)(x1s + ci * X1CI + o1);
      *(float4*)&xv[4] = *(const float4*)(x1s + ci * X1CI + o1 + 4);
      *(float4*)&v[0]  = *(const float4*)(x2s + ci * X2CI + o2);
      *(float4*)&v[4]  = *(const float4*)(x2s + ci * X2CI + o2 + 4);
      *(float4*)&v[8]  = *(const float4*)(x2s + ci * X2CI + o2 + 8);
      *(float4*)&v[12] = *(const float4*)(x2s + ci * X2CI + o2 + 12);
#pragma unroll
      for (int jj = 0; jj < 9; ++jj)
#pragma unroll
        for (int p = 0; p < 8; ++p)
          acc[jj][p] = fmaf(xv[p], v[p + 8 - jj], acc[jj][p]);
    }
  }

  // ---- epilogue: k = (9*(wv-4) + (jj-4)) mod 81 = (9*wv + jj + 41) % 81 ----
  const float s = 1.0f / 81.0f;
#pragma unroll
  for (int jj = 0; jj < 9; ++jj) {
    const int kk = (9 * wv + jj + 41) % 81;
    float* o = out + (((size_t)b * DD + kk) * HH + (h0 + hl)) * WW + w0 + g * 8;
    float4 lo, hi;
    lo.x = acc[jj][0] * s; lo.y = acc[jj][1] * s;
    lo.z = acc[jj][2] * s; lo.w = acc[jj][3] * s;
    hi.x = acc[jj][4] * s; hi.y = acc[jj][5] * s;
    hi.z = acc[jj][6] * s; hi.w = acc[jj][7] * s;
    *(float4*)o = lo;
    *(float4*)(o + 4) = hi;
  }
}

extern "C" void kernel_launch(void* const* d_in, const int* in_sizes, int n_in,
                              void* d_out, int out_size, void* d_ws,
                              size_t ws_size, hipStream_t stream) {
  const float* x1 = (const float*)d_in[0];
  const float* x2 = (const float*)d_in[1];
  float* out = (float*)d_out;

  // zero 256 B of workspace: OOB staging lanes load zeros from here
  hipMemsetAsync(d_ws, 0, 256, stream);

  dim3 grid(WW / TWIDE, HH / TH, 4);  // 4 x 16 x 4 = 256 blocks (1 per CU)
  dim3 block(NT);
  hipLaunchKernelGGL(cost_volume_kernel, grid, block, 0, stream, x1, x2, out,
                     (const float*)d_ws);
}

// Round 3
// 265.388 us; speedup vs baseline: 1.0511x; 1.0511x over previous
//
#include <hip/hip_runtime.h>
#include <stdint.h>

// Cost volume: out[b,k,h,w] = (1/81) * sum_c x1[b,c,h,w] * x2[b,c,h-i,w-j]
// k = (9i+j) mod 81, i,j in [-4,4], zero-padded x2. B=4 C=128 H=128 W=256 fp32.
//
// Round 3 design:
//  - block = 9 waves (576 thr), wave wv -> displacement row i = wv-4.
//  - tile 8h x 64w; lane owns 8 w-pixels -> acc[9][8] = 72 fp32 regs.
//  - x1: global->register direct (2 dwordx4/lane/ch; all 9 waves read the
//    same tile -> L1-served). No LDS, no staging for x1.
//  - x2: double-buffered global_load_lds (16B), CK=8 channels/chunk.
//    LDS rows = 19 groups (18 real + 1 slack) of 16B, XOR-swizzled:
//    phys_grp = grp ^ (row&7) for grp<16. Reader offsets are lane-constant.
//  - __launch_bounds__(576,2): VGPR cap 256 -> NO spill, NO AGPR shuffling
//    (round-2 regression root cause: (576,4) capped unified file at 128 ->
//    64 VGPR + AGPR acc + 62 MB scratch spill traffic).

#define AS1(p) (const __attribute__((address_space(1))) void*)(p)
#define AS3(p) (__attribute__((address_space(3))) void*)(p)

#define HH 128
#define WW 256
#define CCT 128
#define DD 81
#define TH 8
#define TWIDE 64
#define CK 8
#define NT 576
#define X2GRP 19                 // 16B-groups per LDS row (18 used + 1 slack)
#define X2STR (X2GRP * 4)        // 76 words per row
#define X2ROWS 16
#define X2CI (X2ROWS * X2STR)    // 1216 words per channel
#define BUFW (CK * X2CI)         // 9728 words = 38912 B per buffer
#define NGRP (CK * X2ROWS * X2GRP)  // 2432 staging groups per chunk

__global__ __launch_bounds__(NT, 2) void cost_volume_kernel(
    const float* __restrict__ x1, const float* __restrict__ x2,
    float* __restrict__ out, const float* __restrict__ zws) {
  __shared__ float smem[2][BUFW];  // 77824 B

  const int b = blockIdx.z;
  const int h0 = blockIdx.y * TH;
  const int w0 = blockIdx.x * TWIDE;
  const int t = threadIdx.x;
  const int wv = t >> 6;      // 0..8 -> i = wv-4
  const int lane = t & 63;
  const int hl = lane >> 3;   // 0..7 local h row
  const int g = lane & 7;     // 0..7 group of 8 w pixels
  const int r = hl + 8 - wv;  // x2 local row (0..15)

  const float* x1b = x1 + (size_t)b * CCT * HH * WW;
  const float* x2b = x2 + (size_t)b * CCT * HH * WW;

  // ---- stage one CK-channel x2 chunk (halo tile) into buf, async ----
  auto stage = [&](int c0, float* buf) {
#pragma unroll
    for (int it = 0; it < 5; ++it) {
      const int idx = t + it * NT;
      if (idx < NGRP) {  // 2432 = 38 waves: wave-uniform mask
        const int ci = idx / (X2ROWS * X2GRP);
        const int rem = idx - ci * (X2ROWS * X2GRP);
        const int row = rem / X2GRP;
        const int pg = rem - row * X2GRP;            // physical group
        const int lg = (pg < 16) ? (pg ^ (row & 7)) : pg;  // logical group
        const int h = h0 - 4 + row;
        const int w = w0 - 4 + lg * 4;
        const float* gp = zws;
        if ((unsigned)h < (unsigned)HH && (unsigned)w <= (unsigned)(WW - 4))
          gp = x2b + (((size_t)(c0 + ci) * HH + h) << 8) + w;
        __builtin_amdgcn_global_load_lds(AS1(gp), AS3(buf + idx * 4), 16, 0, 0);
      }
    }
  };

  float acc[9][8];
#pragma unroll
  for (int jj = 0; jj < 9; ++jj)
#pragma unroll
    for (int p = 0; p < 8; ++p) acc[jj][p] = 0.f;

  // lane-constant swizzled LDS read offsets (words), one per b128
  const int mask = r & 7;
  int off[4];
#pragma unroll
  for (int q = 0; q < 4; ++q) {
    const int lgq = 2 * g + q;                        // logical group 0..17
    const int pgq = (lgq < 16) ? (lgq ^ mask) : lgq;  // physical group
    off[q] = r * X2STR + pgq * 4;
  }

  // lane's x1 pointer (always in-bounds)
  const float* x1p = x1b + ((size_t)(h0 + hl) << 8) + w0 + g * 8;

  stage(0, smem[0]);

  for (int k = 0; k < CCT / CK; ++k) {
    __syncthreads();  // drains stage(k); protects buffer reuse
    if (k < CCT / CK - 1) stage((k + 1) * CK, smem[(k + 1) & 1]);
    const float* x2s = smem[k & 1];
#pragma unroll
    for (int ci = 0; ci < CK; ++ci) {
      const int c = k * CK + ci;
      float xv[8], v[16];
      *(float4*)&xv[0] = *(const float4*)(x1p + (size_t)c * (HH * WW));
      *(float4*)&xv[4] = *(const float4*)(x1p + (size_t)c * (HH * WW) + 4);
      const float* base = x2s + ci * X2CI;
      *(float4*)&v[0]  = *(const float4*)(base + off[0]);
      *(float4*)&v[4]  = *(const float4*)(base + off[1]);
      *(float4*)&v[8]  = *(const float4*)(base + off[2]);
      *(float4*)&v[12] = *(const float4*)(base + off[3]);
#pragma unroll
      for (int jj = 0; jj < 9; ++jj)
#pragma unroll
        for (int p = 0; p < 8; ++p)
          acc[jj][p] = fmaf(xv[p], v[p + 8 - jj], acc[jj][p]);
    }
  }

  // ---- epilogue: kk = (9*(wv-4) + (jj-4)) mod 81 ----
  const float s = 1.0f / 81.0f;
#pragma unroll
  for (int jj = 0; jj < 9; ++jj) {
    const int kk = (9 * wv + jj + 41) % 81;
    float* o = out + (((size_t)b * DD + kk) * HH + (h0 + hl)) * WW + w0 + g * 8;
    float4 lo, hi;
    lo.x = acc[jj][0] * s; lo.y = acc[jj][1] * s;
    lo.z = acc[jj][2] * s; lo.w = acc[jj][3] * s;
    hi.x = acc[jj][4] * s; hi.y = acc[jj][5] * s;
    hi.z = acc[jj][6] * s; hi.w = acc[jj][7] * s;
    *(float4*)o = lo;
    *(float4*)(o + 4) = hi;
  }
}

extern "C" void kernel_launch(void* const* d_in, const int* in_sizes, int n_in,
                              void* d_out, int out_size, void* d_ws,
                              size_t ws_size, hipStream_t stream) {
  const float* x1 = (const float*)d_in[0];
  const float* x2 = (const float*)d_in[1];
  float* out = (float*)d_out;

  // zero 256 B of workspace: OOB staging lanes load zeros from here
  hipMemsetAsync(d_ws, 0, 256, stream);

  dim3 grid(WW / TWIDE, HH / TH, 4);  // 4 x 16 x 4 = 256 blocks
  dim3 block(NT);
  hipLaunchKernelGGL(cost_volume_kernel, grid, block, 0, stream, x1, x2, out,
                     (const float*)d_ws);
}